// Round 14
// baseline (304.037 us; speedup 1.0000x reference)
//
#include <hip/hip_runtime.h>

#define KTOP 100
#define NCOL 16384
#define TPB  256
#define NIT  (NCOL / 4 / TPB)    // 16 float4 iterations per thread
#define HST  520                 // per-copy hist stride (512 words + 8 pad)
#define CAP  768                 // (bits,col) list capacity (~373 expected for N(0,1))
#define RB0  512u                // __float_as_uint(2.0f) >> 21

// order-preserving key transform (generic fallback only)
__device__ __forceinline__ unsigned enc(unsigned u){ return u ^ (((unsigned)((int)u>>31)) | 0x80000000u); }
__device__ __forceinline__ unsigned dec(unsigned k){ return k ^ ((k & 0x80000000u) ? 0x80000000u : 0xFFFFFFFFu); }
// transposed hist word index: scan's per-lane reads land at stride-64 words -> conflict-free
__device__ __forceinline__ int hw(unsigned b){ return (int)(((b & 7u) << 6) | (b >> 3)); }

__global__ __launch_bounds__(TPB, 8)
void topk_act_kernel(const float* __restrict__ x, float* __restrict__ out) {
    __shared__ unsigned hist[2*HST];     // 4.2 KB; generic path reuses as 256-bin hist / scan space
    __shared__ uint2 cand[CAP];          // 6 KB: (bits, col) of all values >= 2.0
    __shared__ unsigned s_cnt, s_T, s_krem, s_eqc, s_ccut;

    const int tid = threadIdx.x, lane = tid & 63, wv = tid >> 6;
    const int row = blockIdx.x;
    const float4* __restrict__ xr = (const float4*)(x + (size_t)row * NCOL);
    float4* __restrict__ orow = (float4*)(out + (size_t)row * NCOL);

    for (int i = tid; i < 2*HST; i += TPB) hist[i] = 0;
    if (tid == 0) s_cnt = 0;
    __syncthreads();

    // ---- phase 1: stream read (no retention); push (bits,col) of values >= 2.0 ----
    for (int j = 0; j < NIT; ++j) {
        const int i = tid + j*TPB;
        float4 v = xr[i];
        const unsigned col = 4u * (unsigned)i;
        if (v.x >= 2.0f) { unsigned p = atomicAdd(&s_cnt,1u); if (p < CAP) cand[p] = make_uint2(__float_as_uint(v.x), col); }
        if (v.y >= 2.0f) { unsigned p = atomicAdd(&s_cnt,1u); if (p < CAP) cand[p] = make_uint2(__float_as_uint(v.y), col+1u); }
        if (v.z >= 2.0f) { unsigned p = atomicAdd(&s_cnt,1u); if (p < CAP) cand[p] = make_uint2(__float_as_uint(v.z), col+2u); }
        if (v.w >= 2.0f) { unsigned p = atomicAdd(&s_cnt,1u); if (p < CAP) cand[p] = make_uint2(__float_as_uint(v.w), col+3u); }
    }
    __syncthreads();
    const unsigned mcnt = s_cnt;

    unsigned Traw, krem, eqv, ccut = NCOL;
    bool generic = false;

    if (mcnt >= KTOP && mcnt <= CAP) {
        // ---- phase 2: select from the list only ----
        unsigned* hb = hist + (wv & 1) * HST;
        for (unsigned i = tid; i < mcnt; i += TPB)
            atomicAdd(&hb[hw((cand[i].x >> 21) - RB0)], 1u);
        __syncthreads();
        // wave-redundant suffix scan of 512 dual-copy bins (transposed, conflict-free)
        unsigned own = 0;
        #pragma unroll
        for (int w = 0; w < 8; ++w) own += hist[64*w + lane] + hist[HST + 64*w + lane];
        unsigned incl = own;
        #pragma unroll
        for (int s = 1; s < 64; s <<= 1) { unsigned t = __shfl_down(incl, s); if (lane + s < 64) incl += t; }
        const unsigned above = incl - own;
        bool hit = (above < KTOP) && (above + own >= KTOP);
        unsigned long long bal = __ballot(hit);
        int L = __ffsll((long long)bal) - 1;
        unsigned run = __shfl(above, L);
        unsigned sbin = 0, sk = 1, se = 1;
        for (int w = 7; w >= 0; --w) {
            unsigned c = hist[64*w + L] + hist[HST + 64*w + L];
            unsigned rr = run + c;
            if (run < KTOP && rr >= KTOP) { sbin = 8u*(unsigned)L + (unsigned)w; sk = KTOP - run; se = c; }
            run = rr;
        }
        const unsigned pbin = sbin + RB0;
        if (sk == se) {
            Traw = pbin << 21; krem = sk; eqv = se;            // whole bin kept, known locally
        } else {
            // all-pairs rank among boundary-bin entries; STRIDED so every index is examined
            for (unsigned idx = tid; idx < mcnt; idx += TPB) {
                const uint2 c = cand[idx];
                if ((c.x >> 21) != pbin) continue;
                unsigned g = 0, q = 0;
                for (unsigned jj = 0; jj < mcnt; ++jj) {
                    unsigned b = cand[jj].x;
                    if ((b >> 21) == pbin) { g += (b > c.x); q += (b == c.x); }
                }
                if (g < sk && g + q >= sk) {
                    const unsigned kr = sk - g;
                    unsigned cc = NCOL;
                    if (kr < q) {            // stable tie: kr-th smallest col among equals
                        unsigned prev = 0; bool first = true;
                        for (unsigned t2 = 0; t2 < kr; ++t2) {
                            unsigned mn = 0xFFFFFFFFu;
                            for (unsigned jj = 0; jj < mcnt; ++jj) {
                                uint2 e = cand[jj];
                                if (e.x == c.x && (first || e.y > prev) && e.y < mn) mn = e.y;
                            }
                            prev = mn; first = false;
                        }
                        cc = prev + 1;
                    }
                    s_T = c.x; s_krem = kr; s_eqc = q; s_ccut = cc;
                }
            }
            __syncthreads();
            Traw = s_T; krem = s_krem; eqv = s_eqc; ccut = s_ccut;
        }
    } else generic = true;

    if (!generic) {
        // ---- phase 3: re-read (L3-warm) + dense write; stateless predicate ----
        const float fT = __uint_as_float(Traw);
        const unsigned cc = (krem == eqv) ? (unsigned)NCOL : ccut;
        for (int j = 0; j < NIT; ++j) {
            const int i = tid + j*TPB;
            float4 v = xr[i];
            const unsigned col = 4u * (unsigned)i;
            float4 o;
            o.x = (v.x > fT || (v.x == fT && col      < cc)) ? v.x : 0.f;
            o.y = (v.y > fT || (v.y == fT && col+1u   < cc)) ? v.y : 0.f;
            o.z = (v.z > fT || (v.z == fT && col+2u   < cc)) ? v.z : 0.f;
            o.w = (v.w > fT || (v.w == fT && col+3u   < cc)) ? v.w : 0.f;
            orow[i] = o;
        }
    } else {
        // ---- rare generic 4x8-bit radix (any distribution), re-reading global (L3-warm) ----
        unsigned pref = 0, kc = KTOP, eq = 0;
        for (int p = 0; p < 4; ++p) {
            const int shift = 24 - 8*p;
            __syncthreads();
            for (int i = tid; i < 256; i += TPB) hist[i] = 0;
            __syncthreads();
            for (int j = 0; j < NIT; ++j) {
                float4 v = xr[tid + j*TPB];
                unsigned kk;
                kk = enc(__float_as_uint(v.x)); if (p == 0 || ((kk ^ pref) >> (shift+8)) == 0) atomicAdd(&hist[(kk >> shift) & 0xFFu], 1u);
                kk = enc(__float_as_uint(v.y)); if (p == 0 || ((kk ^ pref) >> (shift+8)) == 0) atomicAdd(&hist[(kk >> shift) & 0xFFu], 1u);
                kk = enc(__float_as_uint(v.z)); if (p == 0 || ((kk ^ pref) >> (shift+8)) == 0) atomicAdd(&hist[(kk >> shift) & 0xFFu], 1u);
                kk = enc(__float_as_uint(v.w)); if (p == 0 || ((kk ^ pref) >> (shift+8)) == 0) atomicAdd(&hist[(kk >> shift) & 0xFFu], 1u);
            }
            __syncthreads();
            unsigned t0 = hist[4*lane], t1 = hist[4*lane+1], t2 = hist[4*lane+2], t3 = hist[4*lane+3];
            unsigned own = t0+t1+t2+t3, incl = own;
            #pragma unroll
            for (int s = 1; s < 64; s <<= 1) { unsigned t = __shfl_down(incl, s); if (lane + s < 64) incl += t; }
            unsigned above = incl - own;
            unsigned C3 = above + t3, C2 = C3 + t2, C1 = C2 + t1, C0 = C1 + t0;
            bool h3 = (above < kc) && (C3 >= kc);
            bool h2 = (C3 < kc) && (C2 >= kc);
            bool h1 = (C2 < kc) && (C1 >= kc);
            bool h0 = (C1 < kc) && (C0 >= kc);
            unsigned mybin = h3 ? (4u*lane+3u) : h2 ? (4u*lane+2u) : h1 ? (4u*lane+1u) : (4u*lane);
            unsigned myk   = h3 ? (kc - above) : h2 ? (kc - C3) : h1 ? (kc - C2) : (kc - C1);
            unsigned myeq  = h3 ? t3 : h2 ? t2 : h1 ? t1 : t0;
            unsigned long long bal2 = __ballot(h0|h1|h2|h3);
            int L2 = __ffsll((long long)bal2) - 1;
            pref |= __shfl(mybin, L2) << shift;
            kc    = __shfl(myk, L2);
            eq    = __shfl(myeq, L2);
        }
        __syncthreads();
        if (kc == eq) {
            for (int j = 0; j < NIT; ++j) {
                const int i = tid + j*TPB;
                float4 v = xr[i];
                float4 o;
                o.x = (enc(__float_as_uint(v.x)) >= pref) ? v.x : 0.f;
                o.y = (enc(__float_as_uint(v.y)) >= pref) ? v.y : 0.f;
                o.z = (enc(__float_as_uint(v.z)) >= pref) ? v.z : 0.f;
                o.w = (enc(__float_as_uint(v.w)) >= pref) ? v.w : 0.f;
                orow[i] = o;
            }
        } else {
            // stable tie: block-scan in column order, re-reading global
            unsigned* sa = hist;                 // 1040 words >= TPB
            unsigned runacc = 0;
            for (int j = 0; j < NIT; ++j) {
                const int i = tid + j*TPB;
                float4 v = xr[i];
                unsigned k0 = enc(__float_as_uint(v.x)), k1 = enc(__float_as_uint(v.y));
                unsigned k2 = enc(__float_as_uint(v.z)), k3 = enc(__float_as_uint(v.w));
                unsigned e0 = (k0 == pref), e1 = (k1 == pref), e2 = (k2 == pref), e3 = (k3 == pref);
                unsigned le = e0+e1+e2+e3;
                __syncthreads();
                sa[tid] = le;
                __syncthreads();
                for (int s = 1; s < TPB; s <<= 1) {
                    unsigned t = (tid >= s) ? sa[tid-s] : 0u;
                    __syncthreads();
                    sa[tid] += t;
                    __syncthreads();
                }
                unsigned excl = sa[tid] - le, total = sa[TPB-1];
                unsigned r0 = runacc + excl, r1 = r0+e0, r2 = r1+e1, r3 = r2+e2;
                float4 o;
                o.x = (k0 > pref || (e0 && r0 < kc)) ? v.x : 0.f;
                o.y = (k1 > pref || (e1 && r1 < kc)) ? v.y : 0.f;
                o.z = (k2 > pref || (e2 && r2 < kc)) ? v.z : 0.f;
                o.w = (k3 > pref || (e3 && r3 < kc)) ? v.w : 0.f;
                orow[i] = o;
                runacc += total;
            }
        }
    }
}

extern "C" void kernel_launch(void* const* d_in, const int* in_sizes, int n_in,
                              void* d_out, int out_size, void* d_ws, size_t ws_size,
                              hipStream_t stream) {
    const float* x = (const float*)d_in[0];
    float* out = (float*)d_out;
    const int B = in_sizes[0] / NCOL;   // 4096 rows
    topk_act_kernel<<<B, TPB, 0, stream>>>(x, out);
}

// Round 15
// 195.311 us; speedup vs baseline: 1.5567x; 1.5567x over previous
//
#include <hip/hip_runtime.h>

#define KTOP 100
#define NCOL 16384
#define TPB  256
#define NIT  (NCOL / 4 / TPB)    // 16 float4 iterations per thread
#define HST  520                 // per-copy hist stride (512 words + 8 pad)
#define CAP  768                 // (bits,col) list capacity (~373 expected for N(0,1))
#define RB0  512u                // __float_as_uint(2.0f) >> 21

// order-preserving key transform (generic fallback only)
__device__ __forceinline__ unsigned enc(unsigned u){ return u ^ (((unsigned)((int)u>>31)) | 0x80000000u); }
// transposed hist word index: scan's per-lane reads land at stride-64 words -> conflict-free
__device__ __forceinline__ int hw(unsigned b){ return (int)(((b & 7u) << 6) | (b >> 3)); }

__global__ __launch_bounds__(TPB, 8)
void topk_act_kernel(const float* __restrict__ x, float* __restrict__ out) {
    __shared__ unsigned hist[2*HST];     // 4.2 KB; generic path reuses as 256-bin hist / scan space
    __shared__ uint2 cand[CAP];          // 6 KB: (bits, col) of all values >= 2.0
    __shared__ unsigned s_cnt, s_T, s_krem, s_eqc, s_ccut;

    const int tid = threadIdx.x, lane = tid & 63, wv = tid >> 6;
    const int row = blockIdx.x;
    const float4* __restrict__ xr = (const float4*)(x + (size_t)row * NCOL);
    float4* __restrict__ orow = (float4*)(out + (size_t)row * NCOL);
    float* __restrict__ orow_s = out + (size_t)row * NCOL;

    for (int i = tid; i < 2*HST; i += TPB) hist[i] = 0;
    if (tid == 0) s_cnt = 0;
    __syncthreads();

    // ---- phase 1: stream read + IMMEDIATE dense zero store (full R/W overlap);
    //      push (bits,col) of values >= 2.0 into LDS list ----
    const float4 z4 = make_float4(0.f, 0.f, 0.f, 0.f);
    for (int j = 0; j < NIT; ++j) {
        const int i = tid + j*TPB;
        float4 v = xr[i];
        orow[i] = z4;                                  // dense zero, no dependency
        const unsigned col = 4u * (unsigned)i;
        if (v.x >= 2.0f) { unsigned p = atomicAdd(&s_cnt,1u); if (p < CAP) cand[p] = make_uint2(__float_as_uint(v.x), col); }
        if (v.y >= 2.0f) { unsigned p = atomicAdd(&s_cnt,1u); if (p < CAP) cand[p] = make_uint2(__float_as_uint(v.y), col+1u); }
        if (v.z >= 2.0f) { unsigned p = atomicAdd(&s_cnt,1u); if (p < CAP) cand[p] = make_uint2(__float_as_uint(v.z), col+2u); }
        if (v.w >= 2.0f) { unsigned p = atomicAdd(&s_cnt,1u); if (p < CAP) cand[p] = make_uint2(__float_as_uint(v.w), col+3u); }
    }
    __syncthreads();
    const unsigned mcnt = s_cnt;

    if (mcnt >= KTOP && mcnt <= CAP) {
        // ---- phase 2: select T entirely from the list ----
        unsigned* hb = hist + (wv & 1) * HST;
        for (unsigned i = tid; i < mcnt; i += TPB)
            atomicAdd(&hb[hw((cand[i].x >> 21) - RB0)], 1u);
        __syncthreads();
        // wave-redundant suffix scan of 512 dual-copy bins (transposed, conflict-free)
        unsigned own = 0;
        #pragma unroll
        for (int w = 0; w < 8; ++w) own += hist[64*w + lane] + hist[HST + 64*w + lane];
        unsigned incl = own;
        #pragma unroll
        for (int s = 1; s < 64; s <<= 1) { unsigned t = __shfl_down(incl, s); if (lane + s < 64) incl += t; }
        const unsigned above = incl - own;
        bool hit = (above < KTOP) && (above + own >= KTOP);
        unsigned long long bal = __ballot(hit);
        int L = __ffsll((long long)bal) - 1;
        unsigned run = __shfl(above, L);
        unsigned sbin = 0, sk = 1, se = 1;
        for (int w = 7; w >= 0; --w) {
            unsigned c = hist[64*w + L] + hist[HST + 64*w + L];
            unsigned rr = run + c;
            if (run < KTOP && rr >= KTOP) { sbin = 8u*(unsigned)L + (unsigned)w; sk = KTOP - run; se = c; }
            run = rr;
        }
        const unsigned pbin = sbin + RB0;
        unsigned Traw, krem = sk, eqv = se, ccut = NCOL;
        if (sk == se) {
            Traw = pbin << 21;                           // whole bin kept; known locally by all
        } else {
            // all-pairs rank among boundary-bin entries (strided over full list)
            for (unsigned idx = tid; idx < mcnt; idx += TPB) {
                const uint2 c = cand[idx];
                if ((c.x >> 21) != pbin) continue;
                unsigned g = 0, q = 0;
                for (unsigned jj = 0; jj < mcnt; ++jj) {
                    unsigned b = cand[jj].x;
                    if ((b >> 21) == pbin) { g += (b > c.x); q += (b == c.x); }
                }
                if (g < sk && g + q >= sk) {
                    const unsigned kr = sk - g;
                    unsigned cc = NCOL;
                    if (kr < q) {                        // stable tie: kr-th smallest col among equals
                        unsigned prev = 0; bool first = true;
                        for (unsigned t2 = 0; t2 < kr; ++t2) {
                            unsigned mn = 0xFFFFFFFFu;
                            for (unsigned jj = 0; jj < mcnt; ++jj) {
                                uint2 e = cand[jj];
                                if (e.x == c.x && (first || e.y > prev) && e.y < mn) mn = e.y;
                            }
                            prev = mn; first = false;
                        }
                        cc = prev + 1;
                    }
                    s_T = c.x; s_krem = kr; s_eqc = q; s_ccut = cc;
                }
            }
            __syncthreads();
            Traw = s_T; krem = s_krem; eqv = s_eqc; ccut = s_ccut;
        }

        // ---- phase 3: scatter winners over the zeroed row (zero-stores drained by barriers) ----
        __syncthreads();                                 // ensure all waves' zero stores retired
        const unsigned cc = (krem == eqv) ? (unsigned)NCOL : ccut;
        for (unsigned idx = tid; idx < mcnt; idx += TPB) {
            const uint2 c = cand[idx];
            if (c.x > Traw || (c.x == Traw && c.y < cc))
                orow_s[c.y] = __uint_as_float(c.x);      // ~100 stores into L2-dirty lines
        }
    } else {
        // ---- rare generic path (any distribution): 4x8-bit radix, re-read global, dense rewrite ----
        unsigned pref = 0, kc = KTOP, eq = 0;
        for (int p = 0; p < 4; ++p) {
            const int shift = 24 - 8*p;
            __syncthreads();
            for (int i = tid; i < 256; i += TPB) hist[i] = 0;
            __syncthreads();
            for (int j = 0; j < NIT; ++j) {
                float4 v = xr[tid + j*TPB];
                unsigned kk;
                kk = enc(__float_as_uint(v.x)); if (p == 0 || ((kk ^ pref) >> (shift+8)) == 0) atomicAdd(&hist[(kk >> shift) & 0xFFu], 1u);
                kk = enc(__float_as_uint(v.y)); if (p == 0 || ((kk ^ pref) >> (shift+8)) == 0) atomicAdd(&hist[(kk >> shift) & 0xFFu], 1u);
                kk = enc(__float_as_uint(v.z)); if (p == 0 || ((kk ^ pref) >> (shift+8)) == 0) atomicAdd(&hist[(kk >> shift) & 0xFFu], 1u);
                kk = enc(__float_as_uint(v.w)); if (p == 0 || ((kk ^ pref) >> (shift+8)) == 0) atomicAdd(&hist[(kk >> shift) & 0xFFu], 1u);
            }
            __syncthreads();
            unsigned t0 = hist[4*lane], t1 = hist[4*lane+1], t2 = hist[4*lane+2], t3 = hist[4*lane+3];
            unsigned own = t0+t1+t2+t3, incl = own;
            #pragma unroll
            for (int s = 1; s < 64; s <<= 1) { unsigned t = __shfl_down(incl, s); if (lane + s < 64) incl += t; }
            unsigned above = incl - own;
            unsigned C3 = above + t3, C2 = C3 + t2, C1 = C2 + t1, C0 = C1 + t0;
            bool h3 = (above < kc) && (C3 >= kc);
            bool h2 = (C3 < kc) && (C2 >= kc);
            bool h1 = (C2 < kc) && (C1 >= kc);
            bool h0 = (C1 < kc) && (C0 >= kc);
            unsigned mybin = h3 ? (4u*lane+3u) : h2 ? (4u*lane+2u) : h1 ? (4u*lane+1u) : (4u*lane);
            unsigned myk   = h3 ? (kc - above) : h2 ? (kc - C3) : h1 ? (kc - C2) : (kc - C1);
            unsigned myeq  = h3 ? t3 : h2 ? t2 : h1 ? t1 : t0;
            unsigned long long bal2 = __ballot(h0|h1|h2|h3);
            int L2 = __ffsll((long long)bal2) - 1;
            pref |= __shfl(mybin, L2) << shift;
            kc    = __shfl(myk, L2);
            eq    = __shfl(myeq, L2);
        }
        __syncthreads();
        if (kc == eq) {
            for (int j = 0; j < NIT; ++j) {
                const int i = tid + j*TPB;
                float4 v = xr[i];
                float4 o;
                o.x = (enc(__float_as_uint(v.x)) >= pref) ? v.x : 0.f;
                o.y = (enc(__float_as_uint(v.y)) >= pref) ? v.y : 0.f;
                o.z = (enc(__float_as_uint(v.z)) >= pref) ? v.z : 0.f;
                o.w = (enc(__float_as_uint(v.w)) >= pref) ? v.w : 0.f;
                orow[i] = o;
            }
        } else {
            // stable tie: block-scan in column order, re-reading global
            unsigned* sa = hist;                 // 1040 words >= TPB
            unsigned runacc = 0;
            for (int j = 0; j < NIT; ++j) {
                const int i = tid + j*TPB;
                float4 v = xr[i];
                unsigned k0 = enc(__float_as_uint(v.x)), k1 = enc(__float_as_uint(v.y));
                unsigned k2 = enc(__float_as_uint(v.z)), k3 = enc(__float_as_uint(v.w));
                unsigned e0 = (k0 == pref), e1 = (k1 == pref), e2 = (k2 == pref), e3 = (k3 == pref);
                unsigned le = e0+e1+e2+e3;
                __syncthreads();
                sa[tid] = le;
                __syncthreads();
                for (int s = 1; s < TPB; s <<= 1) {
                    unsigned t = (tid >= s) ? sa[tid-s] : 0u;
                    __syncthreads();
                    sa[tid] += t;
                    __syncthreads();
                }
                unsigned excl = sa[tid] - le, total = sa[TPB-1];
                unsigned r0 = runacc + excl, r1 = r0+e0, r2 = r1+e1, r3 = r2+e2;
                float4 o;
                o.x = (k0 > pref || (e0 && r0 < kc)) ? v.x : 0.f;
                o.y = (k1 > pref || (e1 && r1 < kc)) ? v.y : 0.f;
                o.z = (k2 > pref || (e2 && r2 < kc)) ? v.z : 0.f;
                o.w = (k3 > pref || (e3 && r3 < kc)) ? v.w : 0.f;
                orow[i] = o;
                runacc += total;
            }
        }
    }
}

extern "C" void kernel_launch(void* const* d_in, const int* in_sizes, int n_in,
                              void* d_out, int out_size, void* d_ws, size_t ws_size,
                              hipStream_t stream) {
    const float* x = (const float*)d_in[0];
    float* out = (float*)d_out;
    const int B = in_sizes[0] / NCOL;   // 4096 rows
    topk_act_kernel<<<B, TPB, 0, stream>>>(x, out);
}